// Round 17
// baseline (151.283 us; speedup 1.0000x reference)
//
#include <hip/hip_runtime.h>

// mRNN B=128, C=64, H=32, T=256 via MFMA 16x16x32 bf16, split-bf16 (hi+lo).
// R19 (RESUBMIT x2 — GPUAcquisitionTimeouts, never measured).
// R19 = R18 with the permlane32_swap RESULT-PAIR BUG FIXED.
// R18 FAILED validation (absmax 1.85e6): __builtin_amdgcn_permlane32_swap
// returns {vdst_new, vsrc_new} with, for args (old, src):
//   vdst_new[i<32]=old[i<32]; vdst_new[i>=32]=src[i-32];
//   vsrc_new[i<32]=old[i+32]; vsrc_new[i>=32]=src[i>=32].
// With (v,v), pr[0][i<32] = v[i<32] -> lanes 0..15 summed THEIR OWN half
// twice and never saw lanes 32..63 (self-doubling = observed 1.85e6 sig).
// The exchanged value is pr[1]: pr[1][i<32] = v[i+32] = x[lane^32] for the
// storing lanes (q==0). Fix: read pr[1]. Bit-exact same FP sum as
// __shfl_xor(.,32) for lanes < 32.
//
//  (1) cross-q reduction stage 2: 8x ds_bpermute (LDS pipe, lgkmcnt waits at
//      each 8-step tail) -> v_permlane32_swap_b32 (pure VALU).
//      m255: permlane 1.20x vs ds_bpermute for lane[i]<->lane[i+32].
//
// R17 post-mortem: lo-truncate + repack-first = -4.1 µs scan, absmax
// unchanged -> the loop-carried acc->Bh/Bl->MFMA chain is the live lever;
// issue-count and ILP levers are dead (R15 null, R16 regression).
//
// Hard constraints learned this + previous session:
//  - DO NOT template/dual-inline on dir (R6/R7 fail validation; R8 passes).
//  - DO NOT duplicate lanes for occupancy (R9: shared issue port, 2x demand).
//  - DO NOT split a chain across waves (R11: barrier + LDS round-trip).
//  - DO NOT flatten the MFMA tree to depth 1 (R13: 77.9 -> 86.2 µs scan;
//    keep C-operand chaining inside the matrix pipe).
//  - DO NOT trade grid parallelism for per-wave ILP (R16: scan 76->128 µs;
//    1024 single-wave blocks exactly tile the 1024 SIMDs).
//  - permlane32_swap: the exchanged half lives in the SECOND result (pr[1]),
//    not the first (R18 fail).
//
// Layout-closed recurrence (R3/R5/R8-verified): h kept as B-operand fragment;
// row perm rho(m)=8*(m>>2)+(m&3) (+4 tile1) makes lane (q,n)'s C/D output
// exactly its next-step B fragment. No LDS anywhere in the recurrence.
//
// Precision: W=Whi+Wlo (lo RNE), h=hhi+hlo (hi truncate, lo truncate —
// R17-verified absmax 4096 < 15155 thr).
constexpr int Bn = 128, Cn = 64, Hn = 32, Tn = 256;

typedef __attribute__((ext_vector_type(8))) short short8;
typedef __attribute__((ext_vector_type(2))) float f32x2;
typedef __attribute__((ext_vector_type(4))) float f32x4;
typedef __attribute__((ext_vector_type(2))) unsigned int u32x2;
typedef __attribute__((ext_vector_type(4))) unsigned int u32x4;

// pack top16(y):top16(x) -> one u32 (low half = x's top16)
__device__ __forceinline__ unsigned pk_hi(unsigned y, unsigned x) {
  return __builtin_amdgcn_perm(y, x, 0x07060302u);
}

__device__ __forceinline__ void wsplit(float w, short& hi, short& lo) {
  unsigned u = __float_as_uint(w);
  float r = w - __uint_as_float(u & 0xffff0000u);   // exact residual
  unsigned ru = __float_as_uint(r) + 0x8000u;       // RNE-ish lo (weights: keep)
  hi = (short)(u >> 16);
  lo = (short)(ru >> 16);
}

__global__ __launch_bounds__(64, 1)
void mrnn_scan(const float* __restrict__ x, const float* __restrict__ m,
               const float* __restrict__ d,
               const float* __restrict__ Wf, const float* __restrict__ Vf,
               const float* __restrict__ cf,
               const float* __restrict__ Wb, const float* __restrict__ Vb,
               const float* __restrict__ cb,
               const float* __restrict__ U,
               float* __restrict__ pf_out, float* __restrict__ pb_out) {
  const int bid = blockIdx.x;
  const int dir = bid >> 9;                 // 0 fwd, 1 bwd
  const int c   = (bid >> 3) & (Cn - 1);
  const int g   = bid & 7;                  // batch group of 16
  const int tid = threadIdx.x;              // 0..63, one wave
  const int q = tid >> 4;
  const int n = tid & 15;
  const int b = g * 16 + n;

  const float* W  = dir ? Wb : Wf;
  const float* V  = dir ? Vb : Vf;
  const float* cc = dir ? cb : cf;

  // ---- A fragments: A[m=lane&15][k=8q+j], row perm rho(m)=8*(m>>2)+(m&3)
  const int ra0 = 8 * (n >> 2) + (n & 3);
  const int ra1 = ra0 + 4;
  short8 A0h, A0l, A1h, A1l;
#pragma unroll
  for (int j = 0; j < 8; ++j) {
    short hi, lo;
    wsplit(W[(c * Hn + ra0) * Hn + 8 * q + j], hi, lo); A0h[j] = hi; A0l[j] = lo;
    wsplit(W[(c * Hn + ra1) * Hn + 8 * q + j], hi, lo); A1h[j] = hi; A1l[j] = lo;
  }

  // ---- per-lane D rows as 4-wide vectors: tile0 -> 8q+r, tile1 -> 8q+4+r
  f32x4 v0xv, v0yv, v0zv, bs0v, uu0v;
  f32x4 v1xv, v1yv, v1zv, bs1v, uu1v;
#pragma unroll
  for (int r = 0; r < 4; ++r) {
    const int row0 = 8 * q + r, row1 = row0 + 4;
    const float* vp0 = V + (c * Hn + row0) * 3;
    v0xv[r] = vp0[0]; v0yv[r] = vp0[1]; v0zv[r] = vp0[2];
    bs0v[r] = cc[c * Hn + row0];
    uu0v[r] = U[c * 2 * Hn + dir * Hn + row0];
    const float* vp1 = V + (c * Hn + row1) * 3;
    v1xv[r] = vp1[0]; v1yv[r] = vp1[1]; v1zv[r] = vp1[2];
    bs1v[r] = cc[c * Hn + row1];
    uu1v[r] = U[c * 2 * Hn + dir * Hn + row1];
  }

  // ---- state (B fragments)
  u32x4 Bh = {0u, 0u, 0u, 0u};
  u32x4 Bl = {0u, 0u, 0u, 0u};
  const f32x4 z4 = {0.f, 0.f, 0.f, 0.f};

  const long base = ((long)b * Cn + c) * Tn;
  const float* px = x + base;
  const float* pm = m + base;
  const float* pd = d + base;
  float* pout = (dir ? pb_out : pf_out) + base;

  // input schedule (verified): fwd step t reads idx max(t-1,0);
  // bwd step s reads idx min(T-s, T-1). Carry + aligned 8-wide prefetch.
  float cx, cm2, cd2;
  f32x4 qx0, qx1, qm0, qm1, qd0, qd1;
  if (!dir) {
    cx = px[0]; cm2 = pm[0]; cd2 = pd[0];
    qx0 = *(const f32x4*)px;        qx1 = *(const f32x4*)(px + 4);
    qm0 = *(const f32x4*)pm;        qm1 = *(const f32x4*)(pm + 4);
    qd0 = *(const f32x4*)pd;        qd1 = *(const f32x4*)(pd + 4);
  } else {
    cx = px[Tn - 1]; cm2 = pm[Tn - 1]; cd2 = pd[Tn - 1];
    qx0 = *(const f32x4*)(px + Tn - 8); qx1 = *(const f32x4*)(px + Tn - 4);
    qm0 = *(const f32x4*)(pm + Tn - 8); qm1 = *(const f32x4*)(pm + Tn - 4);
    qd0 = *(const f32x4*)(pd + Tn - 8); qd1 = *(const f32x4*)(pd + Tn - 4);
  }

  for (int t0 = 0; t0 < Tn; t0 += 8) {
    int qn_ = dir ? (Tn - 16 - t0) : (t0 + 8);
    if (qn_ < 0) qn_ = 0;
    if (qn_ > Tn - 8) qn_ = Tn - 8;
    const f32x4 nx0 = *(const f32x4*)(px + qn_), nx1 = *(const f32x4*)(px + qn_ + 4);
    const f32x4 nm0 = *(const f32x4*)(pm + qn_), nm1 = *(const f32x4*)(pm + qn_ + 4);
    const f32x4 nd0 = *(const f32x4*)(pd + qn_), nd1 = *(const f32x4*)(pd + qn_ + 4);

    // v[0..7] = the 8 loaded values per stream
    float vxa[8] = {qx0.x, qx0.y, qx0.z, qx0.w, qx1.x, qx1.y, qx1.z, qx1.w};
    float vma[8] = {qm0.x, qm0.y, qm0.z, qm0.w, qm1.x, qm1.y, qm1.z, qm1.w};
    float vda[8] = {qd0.x, qd0.y, qd0.z, qd0.w, qd1.x, qd1.y, qd1.z, qd1.w};
    float inx[8], inm[8], ind[8];
    inx[0] = cx; inm[0] = cm2; ind[0] = cd2;
    if (!dir) {
#pragma unroll
      for (int k = 1; k < 8; ++k) {
        inx[k] = vxa[k - 1]; inm[k] = vma[k - 1]; ind[k] = vda[k - 1];
      }
      cx = vxa[7]; cm2 = vma[7]; cd2 = vda[7];
    } else {
#pragma unroll
      for (int k = 1; k < 8; ++k) {
        inx[k] = vxa[8 - k]; inm[k] = vma[8 - k]; ind[k] = vda[8 - k];
      }
      cx = vxa[0]; cm2 = vma[0]; cd2 = vda[0];
    }

    float pacc[8];
#pragma unroll
    for (int u = 0; u < 8; ++u) {
      const float ix = inx[u], im = inm[u], idv = ind[u];
      const f32x4 ix4 = {ix, ix, ix, ix};
      const f32x4 im4 = {im, im, im, im};
      const f32x4 id4 = {idv, idv, idv, idv};
      f32x4 vi0 = __builtin_elementwise_fma(v0xv, ix4,
                    __builtin_elementwise_fma(v0yv, im4,
                      __builtin_elementwise_fma(v0zv, id4, bs0v)));
      f32x4 vi1 = __builtin_elementwise_fma(v1xv, ix4,
                    __builtin_elementwise_fma(v1yv, im4,
                      __builtin_elementwise_fma(v1zv, id4, bs1v)));
      const short8 bh = __builtin_bit_cast(short8, Bh);
      const short8 bl = __builtin_bit_cast(short8, Bl);
      // R12/R14 shape (kept): two depth-2 MFMA chains per tile:
      //   side = Wlo@hh + vinit -> + Whi@hl   (small terms, C-chained)
      //   main = Whi@hh + 0                    (big term, depth 1)
      f32x4 s0 = __builtin_amdgcn_mfma_f32_16x16x32_bf16(A0l, bh, vi0, 0, 0, 0);
      f32x4 s1 = __builtin_amdgcn_mfma_f32_16x16x32_bf16(A1l, bh, vi1, 0, 0, 0);
      f32x4 a0 = __builtin_amdgcn_mfma_f32_16x16x32_bf16(A0h, bh, z4, 0, 0, 0);
      f32x4 a1 = __builtin_amdgcn_mfma_f32_16x16x32_bf16(A1h, bh, z4, 0, 0, 0);
      s0 = __builtin_amdgcn_mfma_f32_16x16x32_bf16(A0h, bl, s0, 0, 0, 0);
      s1 = __builtin_amdgcn_mfma_f32_16x16x32_bf16(A1h, bl, s1, 0, 0, 0);
      f32x4 acc0 = __builtin_elementwise_max(a0 + s0, z4);
      f32x4 acc1 = __builtin_elementwise_max(a1 + s1, z4);
      // repack FIRST (loop-carried path), U-projection after.
      // hi = truncate via v_perm; lo = TRUNCATED exact residual
      const unsigned h00 = __float_as_uint(acc0[0]), h01 = __float_as_uint(acc0[1]);
      const unsigned h02 = __float_as_uint(acc0[2]), h03 = __float_as_uint(acc0[3]);
      const unsigned h10 = __float_as_uint(acc1[0]), h11 = __float_as_uint(acc1[1]);
      const unsigned h12 = __float_as_uint(acc1[2]), h13 = __float_as_uint(acc1[3]);
      Bh[0] = pk_hi(h01, h00); Bh[1] = pk_hi(h03, h02);
      Bh[2] = pk_hi(h11, h10); Bh[3] = pk_hi(h13, h12);
      unsigned ru[8];
#pragma unroll
      for (int r = 0; r < 4; ++r) {
        ru[r]     = __float_as_uint(acc0[r] - __uint_as_float(__float_as_uint(acc0[r]) & 0xffff0000u));
        ru[4 + r] = __float_as_uint(acc1[r] - __uint_as_float(__float_as_uint(acc1[r]) & 0xffff0000u));
      }
      Bl[0] = pk_hi(ru[1], ru[0]); Bl[1] = pk_hi(ru[3], ru[2]);
      Bl[2] = pk_hi(ru[5], ru[4]); Bl[3] = pk_hi(ru[7], ru[6]);
      // U partial as tree (off the loop-carried path)
      f32x4 pp = uu0v * acc0;
      pp = __builtin_elementwise_fma(uu1v, acc1, pp);
      const f32x2 ph = __builtin_shufflevector(pp, pp, 0, 1) +
                       __builtin_shufflevector(pp, pp, 2, 3);
      pacc[u] = ph[0] + ph[1];
    }
    // batched cross-q reduction: 8 independent xor-16 (ds_swizzle), then
    // R19: 8 permlane32_swap (VALU); exchanged half is pr[1]:
    // pr[1][i<32] = v[i+32] — valid exactly where stores happen (q==0).
#pragma unroll
    for (int u = 0; u < 8; ++u) pacc[u] += __shfl_xor(pacc[u], 16);
#pragma unroll
    for (int u = 0; u < 8; ++u) {
      const unsigned v = __float_as_uint(pacc[u]);
      const u32x2 pr = __builtin_amdgcn_permlane32_swap(v, v, false, false);
      pacc[u] += __uint_as_float(pr[1]);
    }

    if (q == 0) {
      if (!dir) {
        f32x4 o0 = {pacc[0], pacc[1], pacc[2], pacc[3]};
        f32x4 o1 = {pacc[4], pacc[5], pacc[6], pacc[7]};
        *(f32x4*)(pout + t0) = o0;
        *(f32x4*)(pout + t0 + 4) = o1;
      } else {
        // positions Tn-8-t0+j hold step t0+(7-j)  (pre-reversed)
        f32x4 o0 = {pacc[7], pacc[6], pacc[5], pacc[4]};
        f32x4 o1 = {pacc[3], pacc[2], pacc[1], pacc[0]};
        *(f32x4*)(pout + (Tn - 8 - t0)) = o0;
        *(f32x4*)(pout + (Tn - 4 - t0)) = o1;
      }
    }
    qx0 = nx0; qx1 = nx1; qm0 = nm0; qm1 = nm1; qd0 = nd0; qd1 = nd1;
  }
}

// out[i] = relu(pf[i] + pb[i] + c0[c]); pf staged in d_out, pb pre-reversed.
__global__ __launch_bounds__(256)
void mrnn_combine(const float* __restrict__ pb, const float* __restrict__ c0,
                  float* __restrict__ out) {
  const int i4 = blockIdx.x * 256 + threadIdx.x;
  const int c = (i4 >> 6) & (Cn - 1);
  const float c0v = c0[c];
  float4 a = ((const float4*)out)[i4];
  const float4 bb = ((const float4*)pb)[i4];
  a.x = fmaxf(a.x + bb.x + c0v, 0.f);
  a.y = fmaxf(a.y + bb.y + c0v, 0.f);
  a.z = fmaxf(a.z + bb.z + c0v, 0.f);
  a.w = fmaxf(a.w + bb.w + c0v, 0.f);
  ((float4*)out)[i4] = a;
}

extern "C" void kernel_launch(void* const* d_in, const int* in_sizes, int n_in,
                              void* d_out, int out_size, void* d_ws, size_t ws_size,
                              hipStream_t stream) {
  const float* x  = (const float*)d_in[0];
  const float* m  = (const float*)d_in[1];
  const float* dd = (const float*)d_in[2];
  const float* Wf = (const float*)d_in[3];
  const float* Vf = (const float*)d_in[4];
  const float* cf = (const float*)d_in[5];
  const float* Wb = (const float*)d_in[6];
  const float* Vb = (const float*)d_in[7];
  const float* cb = (const float*)d_in[8];
  const float* U  = (const float*)d_in[9];
  const float* c0 = (const float*)d_in[10];
  float* out = (float*)d_out;
  float* pb  = (float*)d_ws;   // B*C*T floats = 8 MB scratch

  mrnn_scan<<<1024, 64, 0, stream>>>(x, m, dd, Wf, Vf, cf, Wb, Vb, cb, U, out, pb);
  mrnn_combine<<<(Bn * Cn * Tn) / (256 * 4), 256, 0, stream>>>(pb, c0, out);
}

// Round 18
// 149.671 us; speedup vs baseline: 1.0108x; 1.0108x over previous
//
#include <hip/hip_runtime.h>

// mRNN B=128, C=64, H=32, T=256 via MFMA 16x16x32 bf16, split-bf16 (hi+lo).
// R20 = REVERT to R17 exactly (session champion: 150.87 µs total, 72.3 µs
// scan, absmax 4096, VGPR 88).
//
// R19 POST-MORTEM (passed, 151.3 total, scan 75.9 — slight scan regression):
//  permlane32_swap (VALU) replaced ds_bpermute (LDS pipe) in the xor-32
//  reduction stage. The reduction tail only feeds pacc (output path, NOT
//  loop-carried), so ds_bpermute's latency hid under independent recurrence
//  work on the IDLE LDS pipe; permlane moved it onto the ~56%-busy VALU
//  pipe. Pipe-balance lesson: prefer the idle pipe for off-critical-path
//  work, even if the instruction is nominally slower (m255 measured the
//  primitive in a VALU-bound µbench — wrong regime for this kernel).
//
// Session ledger (all measured):
//  R13 depth-1 MFMA tree: scan 77.9->86.2 ✗ | R14 revert ✓ | R15 pk-f32
//  vectors: ~null (-1.5, VGPR 104->88) | R16 2-chain/wave: scan->127.6 ✗✗
//  (halved grid; 1024 single-wave blocks exactly tile the 1024 SIMDs) |
//  R17 lo-truncate + repack-first: scan 76.4->72.3 ✓ | R18 permlane pr[0]:
//  FAIL absmax 1.85e6 | R19 permlane pr[1]: correct but scan +3.5 ✗.
//
// Hard constraints (measured, this + previous session):
//  - DO NOT template/dual-inline on dir (R6/R7 fail validation; R8 passes).
//  - DO NOT duplicate lanes for occupancy (R9: shared issue port, 2x demand).
//  - DO NOT split a chain across waves (R11: barrier + LDS round-trip).
//  - DO NOT flatten the MFMA tree to depth 1 (R13; keep C-operand chaining).
//  - DO NOT trade grid parallelism for per-wave ILP (R16).
//  - Reduction tail: keep ds_bpermute (idle LDS pipe), not permlane (R19).
//
// Layout-closed recurrence (R3/R5/R8-verified): h kept as B-operand fragment;
// row perm rho(m)=8*(m>>2)+(m&3) (+4 tile1) makes lane (q,n)'s C/D output
// exactly its next-step B fragment. No LDS anywhere in the recurrence.
//
// Precision: W=Whi+Wlo (lo RNE), h=hhi+hlo (hi truncate, lo truncate —
// R17-verified absmax 4096 < 15155 thr).
constexpr int Bn = 128, Cn = 64, Hn = 32, Tn = 256;

typedef __attribute__((ext_vector_type(8))) short short8;
typedef __attribute__((ext_vector_type(2))) float f32x2;
typedef __attribute__((ext_vector_type(4))) float f32x4;
typedef __attribute__((ext_vector_type(4))) unsigned int u32x4;

// pack top16(y):top16(x) -> one u32 (low half = x's top16)
__device__ __forceinline__ unsigned pk_hi(unsigned y, unsigned x) {
  return __builtin_amdgcn_perm(y, x, 0x07060302u);
}

__device__ __forceinline__ void wsplit(float w, short& hi, short& lo) {
  unsigned u = __float_as_uint(w);
  float r = w - __uint_as_float(u & 0xffff0000u);   // exact residual
  unsigned ru = __float_as_uint(r) + 0x8000u;       // RNE-ish lo (weights: keep)
  hi = (short)(u >> 16);
  lo = (short)(ru >> 16);
}

__global__ __launch_bounds__(64, 1)
void mrnn_scan(const float* __restrict__ x, const float* __restrict__ m,
               const float* __restrict__ d,
               const float* __restrict__ Wf, const float* __restrict__ Vf,
               const float* __restrict__ cf,
               const float* __restrict__ Wb, const float* __restrict__ Vb,
               const float* __restrict__ cb,
               const float* __restrict__ U,
               float* __restrict__ pf_out, float* __restrict__ pb_out) {
  const int bid = blockIdx.x;
  const int dir = bid >> 9;                 // 0 fwd, 1 bwd
  const int c   = (bid >> 3) & (Cn - 1);
  const int g   = bid & 7;                  // batch group of 16
  const int tid = threadIdx.x;              // 0..63, one wave
  const int q = tid >> 4;
  const int n = tid & 15;
  const int b = g * 16 + n;

  const float* W  = dir ? Wb : Wf;
  const float* V  = dir ? Vb : Vf;
  const float* cc = dir ? cb : cf;

  // ---- A fragments: A[m=lane&15][k=8q+j], row perm rho(m)=8*(m>>2)+(m&3)
  const int ra0 = 8 * (n >> 2) + (n & 3);
  const int ra1 = ra0 + 4;
  short8 A0h, A0l, A1h, A1l;
#pragma unroll
  for (int j = 0; j < 8; ++j) {
    short hi, lo;
    wsplit(W[(c * Hn + ra0) * Hn + 8 * q + j], hi, lo); A0h[j] = hi; A0l[j] = lo;
    wsplit(W[(c * Hn + ra1) * Hn + 8 * q + j], hi, lo); A1h[j] = hi; A1l[j] = lo;
  }

  // ---- per-lane D rows as 4-wide vectors: tile0 -> 8q+r, tile1 -> 8q+4+r
  f32x4 v0xv, v0yv, v0zv, bs0v, uu0v;
  f32x4 v1xv, v1yv, v1zv, bs1v, uu1v;
#pragma unroll
  for (int r = 0; r < 4; ++r) {
    const int row0 = 8 * q + r, row1 = row0 + 4;
    const float* vp0 = V + (c * Hn + row0) * 3;
    v0xv[r] = vp0[0]; v0yv[r] = vp0[1]; v0zv[r] = vp0[2];
    bs0v[r] = cc[c * Hn + row0];
    uu0v[r] = U[c * 2 * Hn + dir * Hn + row0];
    const float* vp1 = V + (c * Hn + row1) * 3;
    v1xv[r] = vp1[0]; v1yv[r] = vp1[1]; v1zv[r] = vp1[2];
    bs1v[r] = cc[c * Hn + row1];
    uu1v[r] = U[c * 2 * Hn + dir * Hn + row1];
  }

  // ---- state (B fragments)
  u32x4 Bh = {0u, 0u, 0u, 0u};
  u32x4 Bl = {0u, 0u, 0u, 0u};
  const f32x4 z4 = {0.f, 0.f, 0.f, 0.f};

  const long base = ((long)b * Cn + c) * Tn;
  const float* px = x + base;
  const float* pm = m + base;
  const float* pd = d + base;
  float* pout = (dir ? pb_out : pf_out) + base;

  // input schedule (verified): fwd step t reads idx max(t-1,0);
  // bwd step s reads idx min(T-s, T-1). Carry + aligned 8-wide prefetch.
  float cx, cm2, cd2;
  f32x4 qx0, qx1, qm0, qm1, qd0, qd1;
  if (!dir) {
    cx = px[0]; cm2 = pm[0]; cd2 = pd[0];
    qx0 = *(const f32x4*)px;        qx1 = *(const f32x4*)(px + 4);
    qm0 = *(const f32x4*)pm;        qm1 = *(const f32x4*)(pm + 4);
    qd0 = *(const f32x4*)pd;        qd1 = *(const f32x4*)(pd + 4);
  } else {
    cx = px[Tn - 1]; cm2 = pm[Tn - 1]; cd2 = pd[Tn - 1];
    qx0 = *(const f32x4*)(px + Tn - 8); qx1 = *(const f32x4*)(px + Tn - 4);
    qm0 = *(const f32x4*)(pm + Tn - 8); qm1 = *(const f32x4*)(pm + Tn - 4);
    qd0 = *(const f32x4*)(pd + Tn - 8); qd1 = *(const f32x4*)(pd + Tn - 4);
  }

  for (int t0 = 0; t0 < Tn; t0 += 8) {
    int qn_ = dir ? (Tn - 16 - t0) : (t0 + 8);
    if (qn_ < 0) qn_ = 0;
    if (qn_ > Tn - 8) qn_ = Tn - 8;
    const f32x4 nx0 = *(const f32x4*)(px + qn_), nx1 = *(const f32x4*)(px + qn_ + 4);
    const f32x4 nm0 = *(const f32x4*)(pm + qn_), nm1 = *(const f32x4*)(pm + qn_ + 4);
    const f32x4 nd0 = *(const f32x4*)(pd + qn_), nd1 = *(const f32x4*)(pd + qn_ + 4);

    // v[0..7] = the 8 loaded values per stream
    float vxa[8] = {qx0.x, qx0.y, qx0.z, qx0.w, qx1.x, qx1.y, qx1.z, qx1.w};
    float vma[8] = {qm0.x, qm0.y, qm0.z, qm0.w, qm1.x, qm1.y, qm1.z, qm1.w};
    float vda[8] = {qd0.x, qd0.y, qd0.z, qd0.w, qd1.x, qd1.y, qd1.z, qd1.w};
    float inx[8], inm[8], ind[8];
    inx[0] = cx; inm[0] = cm2; ind[0] = cd2;
    if (!dir) {
#pragma unroll
      for (int k = 1; k < 8; ++k) {
        inx[k] = vxa[k - 1]; inm[k] = vma[k - 1]; ind[k] = vda[k - 1];
      }
      cx = vxa[7]; cm2 = vma[7]; cd2 = vda[7];
    } else {
#pragma unroll
      for (int k = 1; k < 8; ++k) {
        inx[k] = vxa[8 - k]; inm[k] = vma[8 - k]; ind[k] = vda[8 - k];
      }
      cx = vxa[0]; cm2 = vma[0]; cd2 = vda[0];
    }

    float pacc[8];
#pragma unroll
    for (int u = 0; u < 8; ++u) {
      const float ix = inx[u], im = inm[u], idv = ind[u];
      const f32x4 ix4 = {ix, ix, ix, ix};
      const f32x4 im4 = {im, im, im, im};
      const f32x4 id4 = {idv, idv, idv, idv};
      f32x4 vi0 = __builtin_elementwise_fma(v0xv, ix4,
                    __builtin_elementwise_fma(v0yv, im4,
                      __builtin_elementwise_fma(v0zv, id4, bs0v)));
      f32x4 vi1 = __builtin_elementwise_fma(v1xv, ix4,
                    __builtin_elementwise_fma(v1yv, im4,
                      __builtin_elementwise_fma(v1zv, id4, bs1v)));
      const short8 bh = __builtin_bit_cast(short8, Bh);
      const short8 bl = __builtin_bit_cast(short8, Bl);
      // R12/R14 shape (kept): two depth-2 MFMA chains per tile:
      //   side = Wlo@hh + vinit -> + Whi@hl   (small terms, C-chained)
      //   main = Whi@hh + 0                    (big term, depth 1)
      f32x4 s0 = __builtin_amdgcn_mfma_f32_16x16x32_bf16(A0l, bh, vi0, 0, 0, 0);
      f32x4 s1 = __builtin_amdgcn_mfma_f32_16x16x32_bf16(A1l, bh, vi1, 0, 0, 0);
      f32x4 a0 = __builtin_amdgcn_mfma_f32_16x16x32_bf16(A0h, bh, z4, 0, 0, 0);
      f32x4 a1 = __builtin_amdgcn_mfma_f32_16x16x32_bf16(A1h, bh, z4, 0, 0, 0);
      s0 = __builtin_amdgcn_mfma_f32_16x16x32_bf16(A0h, bl, s0, 0, 0, 0);
      s1 = __builtin_amdgcn_mfma_f32_16x16x32_bf16(A1h, bl, s1, 0, 0, 0);
      f32x4 acc0 = __builtin_elementwise_max(a0 + s0, z4);
      f32x4 acc1 = __builtin_elementwise_max(a1 + s1, z4);
      // repack FIRST (loop-carried path), U-projection after.
      // hi = truncate via v_perm; lo = TRUNCATED exact residual
      const unsigned h00 = __float_as_uint(acc0[0]), h01 = __float_as_uint(acc0[1]);
      const unsigned h02 = __float_as_uint(acc0[2]), h03 = __float_as_uint(acc0[3]);
      const unsigned h10 = __float_as_uint(acc1[0]), h11 = __float_as_uint(acc1[1]);
      const unsigned h12 = __float_as_uint(acc1[2]), h13 = __float_as_uint(acc1[3]);
      Bh[0] = pk_hi(h01, h00); Bh[1] = pk_hi(h03, h02);
      Bh[2] = pk_hi(h11, h10); Bh[3] = pk_hi(h13, h12);
      unsigned ru[8];
#pragma unroll
      for (int r = 0; r < 4; ++r) {
        ru[r]     = __float_as_uint(acc0[r] - __uint_as_float(__float_as_uint(acc0[r]) & 0xffff0000u));
        ru[4 + r] = __float_as_uint(acc1[r] - __uint_as_float(__float_as_uint(acc1[r]) & 0xffff0000u));
      }
      Bl[0] = pk_hi(ru[1], ru[0]); Bl[1] = pk_hi(ru[3], ru[2]);
      Bl[2] = pk_hi(ru[5], ru[4]); Bl[3] = pk_hi(ru[7], ru[6]);
      // U partial as tree (off the loop-carried path)
      f32x4 pp = uu0v * acc0;
      pp = __builtin_elementwise_fma(uu1v, acc1, pp);
      const f32x2 ph = __builtin_shufflevector(pp, pp, 0, 1) +
                       __builtin_shufflevector(pp, pp, 2, 3);
      pacc[u] = ph[0] + ph[1];
    }
    // batched cross-q reduction: 8 independent xor-16, then 8 xor-32
    // (ds_swizzle/ds_bpermute — idle LDS pipe; off the loop-carried path)
#pragma unroll
    for (int u = 0; u < 8; ++u) pacc[u] += __shfl_xor(pacc[u], 16);
#pragma unroll
    for (int u = 0; u < 8; ++u) pacc[u] += __shfl_xor(pacc[u], 32);

    if (q == 0) {
      if (!dir) {
        f32x4 o0 = {pacc[0], pacc[1], pacc[2], pacc[3]};
        f32x4 o1 = {pacc[4], pacc[5], pacc[6], pacc[7]};
        *(f32x4*)(pout + t0) = o0;
        *(f32x4*)(pout + t0 + 4) = o1;
      } else {
        // positions Tn-8-t0+j hold step t0+(7-j)  (pre-reversed)
        f32x4 o0 = {pacc[7], pacc[6], pacc[5], pacc[4]};
        f32x4 o1 = {pacc[3], pacc[2], pacc[1], pacc[0]};
        *(f32x4*)(pout + (Tn - 8 - t0)) = o0;
        *(f32x4*)(pout + (Tn - 4 - t0)) = o1;
      }
    }
    qx0 = nx0; qx1 = nx1; qm0 = nm0; qm1 = nm1; qd0 = nd0; qd1 = nd1;
  }
}

// out[i] = relu(pf[i] + pb[i] + c0[c]); pf staged in d_out, pb pre-reversed.
__global__ __launch_bounds__(256)
void mrnn_combine(const float* __restrict__ pb, const float* __restrict__ c0,
                  float* __restrict__ out) {
  const int i4 = blockIdx.x * 256 + threadIdx.x;
  const int c = (i4 >> 6) & (Cn - 1);
  const float c0v = c0[c];
  float4 a = ((const float4*)out)[i4];
  const float4 bb = ((const float4*)pb)[i4];
  a.x = fmaxf(a.x + bb.x + c0v, 0.f);
  a.y = fmaxf(a.y + bb.y + c0v, 0.f);
  a.z = fmaxf(a.z + bb.z + c0v, 0.f);
  a.w = fmaxf(a.w + bb.w + c0v, 0.f);
  ((float4*)out)[i4] = a;
}

extern "C" void kernel_launch(void* const* d_in, const int* in_sizes, int n_in,
                              void* d_out, int out_size, void* d_ws, size_t ws_size,
                              hipStream_t stream) {
  const float* x  = (const float*)d_in[0];
  const float* m  = (const float*)d_in[1];
  const float* dd = (const float*)d_in[2];
  const float* Wf = (const float*)d_in[3];
  const float* Vf = (const float*)d_in[4];
  const float* cf = (const float*)d_in[5];
  const float* Wb = (const float*)d_in[6];
  const float* Vb = (const float*)d_in[7];
  const float* cb = (const float*)d_in[8];
  const float* U  = (const float*)d_in[9];
  const float* c0 = (const float*)d_in[10];
  float* out = (float*)d_out;
  float* pb  = (float*)d_ws;   // B*C*T floats = 8 MB scratch

  mrnn_scan<<<1024, 64, 0, stream>>>(x, m, dd, Wf, Vf, cf, Wb, Vb, cb, U, out, pb);
  mrnn_combine<<<(Bn * Cn * Tn) / (256 * 4), 256, 0, stream>>>(pb, c0, out);
}